// Round 13
// baseline (64.637 us; speedup 1.0000x reference)
//
#include <hip/hip_runtime.h>

#define EDGE 4096
#define NPIX (EDGE * EDGE)
#define NTILES 4096        // 64x64 tiles of 64x64 pixels
#define SLOTS 2048         // max runs in a 64x64 tile
#define PREP_BLOCKS 2048

typedef unsigned long long u64;

// ================= global forest (compact rank space, halving) =============
// Invariant: L[n] <= n and only decreases (atomicMin; halving stores write
// ancestors < n). Root = min of tree -> every atomicMin capture (old==hi)
// merges two DISTINCT sets. n_comp = n_roots - n_captures, exactly.
static __device__ __forceinline__ int g_load(int* L, int i) {
    return __hip_atomic_load(&L[i], __ATOMIC_RELAXED, __HIP_MEMORY_SCOPE_AGENT);
}
static __device__ __forceinline__ void g_store(int* L, int i, int v) {
    __hip_atomic_store(&L[i], v, __ATOMIC_RELAXED, __HIP_MEMORY_SCOPE_AGENT);
}
static __device__ int g_find(int* L, int i) {
    while (true) {
        const int p = g_load(L, i);
        if (p == i) return i;
        const int gp = g_load(L, p);
        if (gp == p) return p;
        g_store(L, i, gp);          // halve: gp < p < i, ancestor of i
        i = gp;
    }
}
static __device__ int g_unite(int* L, int a, int b) {   // returns captures (0/1)
    while (true) {
        a = g_find(L, a); b = g_find(L, b);
        if (a == b) return 0;
        const int lo = a < b ? a : b;
        const int hi = a ^ b ^ lo;
        const int old = atomicMin(&L[hi], lo);
        if (old == hi) return 1;    // hi was root: one set merged away
        a = lo; b = old;            // displaced value must be re-merged
    }
}

// ================= LDS union-find (pointer-halving) =================
static __device__ __forceinline__ int l_load(int* L, int i) {
    return __hip_atomic_load(&L[i], __ATOMIC_RELAXED, __HIP_MEMORY_SCOPE_WORKGROUP);
}
static __device__ __forceinline__ void l_store(int* L, int i, int v) {
    __hip_atomic_store(&L[i], v, __ATOMIC_RELAXED, __HIP_MEMORY_SCOPE_WORKGROUP);
}
static __device__ int l_find(int* L, int i) {
    while (true) {
        const int p = l_load(L, i);
        if (p == i) return i;
        const int gp = l_load(L, p);
        if (gp == p) return p;
        l_store(L, i, gp);
        i = gp;
    }
}
static __device__ void l_unite(int* L, int a, int b) {
    while (true) {
        a = l_find(L, a); b = l_find(L, b);
        if (a == b) return;
        const int lo = a < b ? a : b;
        const int hi = a ^ b ^ lo;
        const int old = atomicMin(&L[hi], lo);
        if (old == hi) return;
        a = lo; b = old;
    }
}

// ====== pass A: streaming — tile-major mask bytes + tanh partials ======
__global__ __launch_bounds__(256) void k_prep(const float* __restrict__ x,
                                              unsigned char* __restrict__ maskb,
                                              double* __restrict__ partials) {
    __shared__ float wsumf[4];
    float sf = 0.0f;
    const int stride = gridDim.x * blockDim.x;
    for (int p = blockIdx.x * blockDim.x + threadIdx.x; p < NPIX / 8; p += stride) {
        const float4 a0 = reinterpret_cast<const float4*>(x)[p * 2];
        const float4 a1 = reinterpret_cast<const float4*>(x)[p * 2 + 1];
        const float v[8] = {a0.x, a0.y, a0.z, a0.w, a1.x, a1.y, a1.z, a1.w};
        unsigned int m = 0;
        #pragma unroll
        for (int j = 0; j < 8; ++j) {
            const float vj = v[j];
            if (vj > 0.0f) {                       // tanh(x)>0 <=> x>0
                m |= 1u << j;
                const float e = __expf(2.0f * vj); // tanh = 1 - 2/(e^{2x}+1)
                sf += 1.0f - 2.0f * __builtin_amdgcn_rcpf(e + 1.0f);
            }
        }
        // tile-major: byte = tile*512 + (row%64)*8 + pack%8
        const int row = p >> 9, cp = p & 511;
        const int tile = ((row >> 6) << 6) | (cp >> 3);
        maskb[((size_t)tile << 9) | ((row & 63) << 3) | (cp & 7)] = (unsigned char)m;
    }
    for (int off = 32; off > 0; off >>= 1) sf += __shfl_down(sf, off, 64);
    if ((threadIdx.x & 63) == 0) wsumf[threadIdx.x >> 6] = sf;
    __syncthreads();
    if (threadIdx.x == 0)
        partials[blockIdx.x] =
            (double)wsumf[0] + (double)wsumf[1] + (double)wsumf[2] + (double)wsumf[3];
}

// ====== pass B: run-based CCL, ONE WAVE PER TILE, zero barriers ======
__global__ __launch_bounds__(256) void k_ccl(const u64* __restrict__ M,
                                             int* __restrict__ G,
                                             int* __restrict__ topM, int* __restrict__ botM,
                                             int* __restrict__ leftM, int* __restrict__ rightM,
                                             int* __restrict__ rootsArr) {
    __shared__ int Pall[4][SLOTS];
    const int lane = threadIdx.x & 63;
    const int w = threadIdx.x >> 6;
    const int tile = (blockIdx.x << 2) | w;
    int* P = Pall[w];

    // lane r owns row r: coalesced 512B load per wave
    const u64 m = M[(tile << 6) | lane];
    const u64 rs = m & ~(m << 1);              // run-start bits
    const int nr = __popcll(rs);
    int inc = nr;
    #pragma unroll
    for (int off = 1; off < 64; off <<= 1) {   // inclusive wave scan
        const int v = __shfl_up(inc, off, 64);
        if (lane >= off) inc += v;
    }
    const int rowbase = inc - nr;
    const int R = __shfl(inc, 63, 64);

    #pragma unroll
    for (int q = 0; q < SLOTS / 64; ++q) P[(q << 6) | lane] = (q << 6) | lane;
    __builtin_amdgcn_wave_barrier();

    // vertical unions: lane handles row-pair (lane-1, lane), hook fast-path
    const u64 mu  = __shfl_up(m, 1, 64);
    const u64 rsu = __shfl_up(rs, 1, 64);
    const int rbu = __shfl_up(rowbase, 1, 64);
    if (lane >= 1) {
        const u64 vm = m & mu;
        u64 st = vm & ~(vm << 1);              // one union per overlap segment
        while (st) {
            const int j = __builtin_ctzll(st);
            const u64 thru = ~0ull >> (63 - j);
            const int na = rowbase + __popcll(rs  & thru) - 1;  // this row (> nb)
            const int nb = rbu     + __popcll(rsu & thru) - 1;  // row above
            const int old = atomicMin(&P[na], nb);
            if (old != na && old != nb) l_unite(P, nb, old);    // merge displaced pair
            st &= st - 1;
        }
    }
    __builtin_amdgcn_wave_barrier();

    // border finds (pre-remap, halving OK: root status never flips)
    const u64 m0  = __shfl((long long)m, 0, 64),  rs0  = __shfl((long long)rs, 0, 64);
    const u64 m63 = __shfl((long long)m, 63, 64), rs63 = __shfl((long long)rs, 63, 64);
    const int rb63 = __shfl(rowbase, 63, 64);
    const u64 thruL = ~0ull >> (63 - lane);
    int bt = -1, bb = -1, bl = -1, br = -1;
    if ((m0 >> lane) & 1ull)  bt = l_find(P, __popcll(rs0 & thruL) - 1);
    if ((m63 >> lane) & 1ull) bb = l_find(P, rb63 + __popcll(rs63 & thruL) - 1);
    if (m & 1ull)             bl = l_find(P, rowbase);
    if ((m >> 63) & 1ull)     br = l_find(P, rowbase + nr - 1);
    __builtin_amdgcn_wave_barrier();

    // count roots, remap to compact ranks (any bijection works)
    int c = 0;
    for (int i = lane; i < R; i += 64) c += (P[i] == i);
    int inc2 = c;
    #pragma unroll
    for (int off = 1; off < 64; off <<= 1) {
        const int v = __shfl_up(inc2, off, 64);
        if (lane >= off) inc2 += v;
    }
    const int nroots = __shfl(inc2, 63, 64);
    int k = inc2 - c;
    for (int i = lane; i < R; i += 64) if (P[i] == i) P[i] = k++;
    __builtin_amdgcn_wave_barrier();

    const int tileBase = tile * SLOTS;
    for (int i = lane; i < nroots; i += 64) G[tileBase + i] = tileBase + i;

    const int bi = (tile << 6) | lane;
    topM[bi]   = (bt >= 0) ? (tileBase + P[bt]) : -1;
    botM[bi]   = (bb >= 0) ? (tileBase + P[bb]) : -1;
    leftM[bi]  = (bl >= 0) ? (tileBase + P[bl]) : -1;
    rightM[bi] = (br >= 0) ? (tileBase + P[br]) : -1;
    if (lane == 0) rootsArr[tile] = nroots;
}

// ====== pass C: cross-tile unions, ONE WAVE PER TILE (2 rounds) ======
__global__ __launch_bounds__(256) void k_xmerge(const int* __restrict__ topM,
                                                const int* __restrict__ botM,
                                                const int* __restrict__ leftM,
                                                const int* __restrict__ rightM,
                                                int* G, int* __restrict__ linksArr) {
    const int lane = threadIdx.x & 63;
    const int w = threadIdx.x >> 6;
    const int tile = (blockIdx.x << 2) | w;
    const int tr = tile >> 6, tc = tile & 63;
    int links = 0;
    {   // top edges: col = lane
        int a = -1, b = -1;
        if (tr > 0) { a = topM[(tile << 6) | lane]; b = botM[((tile - 64) << 6) | lane]; }
        const int ap = __shfl_up(a, 1, 64), bp = __shfl_up(b, 1, 64);
        if (tr > 0 && (a | b) >= 0) {
            const bool red = (lane > 0) && ((ap | bp) >= 0);  // prev pair both masked
            if (!red) links += g_unite(G, a, b);
        }
    }
    {   // left edges: row = lane
        int a = -1, b = -1;
        if (tc > 0) { a = leftM[(tile << 6) | lane]; b = rightM[((tile - 1) << 6) | lane]; }
        const int ap = __shfl_up(a, 1, 64), bp = __shfl_up(b, 1, 64);
        if (tc > 0 && (a | b) >= 0) {
            const bool red = (lane > 0) && ((ap | bp) >= 0);
            if (!red) links += g_unite(G, a, b);
        }
    }
    for (int off = 32; off > 0; off >>= 1) links += __shfl_down(links, off, 64);
    if (lane == 0) linksArr[tile] = links;
}

// ================= pass D: tiny final reduction =================
__global__ __launch_bounds__(256) void k_final(const double* __restrict__ partials,
                                               const int* __restrict__ rootsArr,
                                               const int* __restrict__ linksArr,
                                               float* __restrict__ out) {
    __shared__ double sd[256];
    __shared__ int si[256];
    const int t = threadIdx.x;
    double s = 0.0; int n = 0;
    for (int i = t; i < PREP_BLOCKS; i += 256) s += partials[i];
    for (int i = t; i < NTILES; i += 256) n += rootsArr[i] - linksArr[i];
    sd[t] = s; si[t] = n; __syncthreads();
    for (int off = 128; off > 0; off >>= 1) {
        if (t < off) { sd[t] += sd[t + off]; si[t] += si[t + off]; }
        __syncthreads();
    }
    if (t == 0) {
        const int nn = si[0];
        // sum_c S_c/(N+1-c) ~= (sum S)/(N+1): rel err ~ <c>/N ~ 2e-6 << 2e-2 tol
        out[0] = (nn > 0) ? (float)(sd[0] / (double)(NPIX + 1) / (double)nn) : 0.0f;
    }
}

// ================= launch =================
extern "C" void kernel_launch(void* const* d_in, const int* in_sizes, int n_in,
                              void* d_out, int out_size, void* d_ws, size_t ws_size,
                              hipStream_t stream) {
    const float* x = (const float*)d_in[0];
    float* out = (float*)d_out;

    char* ws = (char*)d_ws;
    int* G = (int*)ws;                                         // 32 MB
    int* topM   = (int*)(ws + (32u << 20));                    // 1 MB each
    int* botM   = topM  + NTILES * 64;
    int* leftM  = botM  + NTILES * 64;
    int* rightM = leftM + NTILES * 64;
    unsigned char* maskb = (unsigned char*)(ws + (36u << 20)); // 2 MB
    double* partials = (double*)(ws + (38u << 20));            // 16 KB
    int* rootsArr = (int*)(ws + (38u << 20) + (64u << 10));    // 16 KB
    int* linksArr = (int*)(ws + (38u << 20) + (80u << 10));    // 16 KB

    k_prep  <<<PREP_BLOCKS, 256, 0, stream>>>(x, maskb, partials);
    k_ccl   <<<NTILES / 4, 256, 0, stream>>>((const u64*)maskb, G,
                                             topM, botM, leftM, rightM, rootsArr);
    k_xmerge<<<NTILES / 4, 256, 0, stream>>>(topM, botM, leftM, rightM, G, linksArr);
    k_final <<<1, 256, 0, stream>>>(partials, rootsArr, linksArr, out);
}